// Round 11
// baseline (55.227 us; speedup 1.0000x reference)
//
#include <hip/hip_runtime.h>
#include <hip/hip_bf16.h>

typedef __attribute__((ext_vector_type(8))) short short8;
typedef __attribute__((ext_vector_type(8))) unsigned short u16x8;
typedef __attribute__((ext_vector_type(4))) unsigned short u16x4;
typedef __attribute__((ext_vector_type(4))) float f32x4;
typedef __attribute__((ext_vector_type(2))) float f32x2;

constexpr int NB = 64;     // batch
constexpr int NL = 96;     // time / conv channels
constexpr int NC = 2048;   // feature / conv spatial
constexpr int TT = 64;     // conv spatial tile per block
constexpr int KTOT = 288;  // conv GEMM K = 96 ch * 3 taps, k = tau*96 + i
constexpr int LROW = 104;  // LDS row pitch in bf16 (52 dw, 16B-aligned rows)
constexpr float LOG2E = 1.44269504088896340736f;

__device__ inline unsigned short f2bf(float f) {
    union { float f; unsigned u; } v; v.f = f;
    unsigned r = v.u + 0x7fff + ((v.u >> 16) & 1);   // RNE
    return (unsigned short)(r >> 16);
}
__device__ inline unsigned cvt_pk_bf16(float lo, float hi) {
    unsigned r;
    asm("v_cvt_pk_bf16_f32 %0, %1, %2" : "=v"(r) : "v"(lo), "v"(hi));
    return r;
}
__device__ inline float fexp2(float x) {
    float r; asm("v_exp_f32 %0, %1" : "=v"(r) : "v"(x)); return r;
}
__device__ inline float frcp(float x) {
    float r; asm("v_rcp_f32 %0, %1" : "=v"(r) : "v"(x)); return r;
}
__device__ inline float bflo(unsigned d) { return __uint_as_float(d << 16); }
__device__ inline float bfhi(unsigned d) { return __uint_as_float(d & 0xffff0000u); }

// ---------------------------------------------------------------------------
// Weight permute+convert: Aw[o][k], k = tau*96 + i, bf16.
// ---------------------------------------------------------------------------
__global__ void prep_aw(const float* __restrict__ w, unsigned short* __restrict__ aw)
{
    int idx = blockIdx.x * 256 + threadIdx.x;
    if (idx >= NL * KTOT) return;
    int o = idx / KTOT, k = idx - o * KTOT;
    int tau = k / NL, i = k - tau * NL;
    aw[idx] = f2bf(w[(o * NL + i) * 3 + tau]);
}

// ---------------------------------------------------------------------------
// winq<Q>: spill-free sliding-window decomp for quarter Q (l = 24Q..24Q+23)
// of one column. <=24 packed-bf16 dwords -> registers (static indices,
// clamp = replicate pad); (s5,s13) kept packed (v_pk_add_f32 updates),
// packed logit fma; softmax gate; mm -> LDS.
// ---------------------------------------------------------------------------
template<int Q>
__device__ __forceinline__ void winq(
    const unsigned* __restrict__ srow,     // &sx[0][c][0], 52-dw row
    unsigned short* __restrict__ mrow,     // &sx[1][c][0]
    f32x2 w01, f32x2 b01, float w2, float b2)
{
    constexpr int L0 = Q * 24;
    constexpr int DW0 = (Q == 0) ? 0 : 12 * Q - 6;
    constexpr int NDW = (Q == 0 || Q == 3) ? 18 : 24;

    unsigned dv[NDW];
#pragma unroll
    for (int d = 0; d < NDW; ++d) dv[d] = srow[DW0 + d];

#define CLMP(r) ((r) < 0 ? 0 : ((r) > 95 ? 95 : (r)))
#define VAL(r) ((CLMP(r) & 1) ? bfhi(dv[(CLMP(r) >> 1) - DW0]) \
                              : bflo(dv[(CLMP(r) >> 1) - DW0]))

    float s5i = 0.0f, s13i = 0.0f, s25 = 0.0f;
#pragma unroll
    for (int d = -12; d <= 12; ++d) {
        float v = VAL(L0 + d);
        s25 += v;
        if (d >= -6 && d <= 6) s13i += v;
        if (d >= -2 && d <= 2) s5i += v;
    }
    f32x2 s513 = {s5i, s13i};

    unsigned md[12];
    float pm = 0.0f;
#pragma unroll
    for (int i = 0; i < 24; ++i) {
        const int l = L0 + i;
        if (i > 0) {
            s25 += VAL(l + 12) - VAL(l - 13);
            s513 += (f32x2){VAL(l + 2), VAL(l + 6)};
            s513 -= (f32x2){VAL(l - 3), VAL(l - 7)};
        }
        float xl = VAL(l);
        f32x2 lg = (f32x2){xl, xl} * w01 + b01;        // v_pk_fma_f32
        float e0 = fexp2(lg.x);
        float e1 = fexp2(lg.y);
        float e2 = fexp2(fmaf(xl, w2, b2));
        float inv = frcp(e0 + e1 + e2);
        float mmv = fmaf(s513.x * 0.2f, e0,
                    fmaf(s513.y * (1.0f / 13.0f), e1,
                         s25 * 0.04f * e2)) * inv;
        if ((i & 1) == 0) pm = mmv;
        else              md[i >> 1] = cvt_pk_bf16(pm, mmv);
    }
#undef VAL
#undef CLMP

#pragma unroll
    for (int v = 0; v < 6; ++v) {
        union { u16x4 vv; unsigned d[2]; } o;
        o.d[0] = md[2 * v]; o.d[1] = md[2 * v + 1];
        *(u16x4*)(mrow + L0 + 4 * v) = o.vv;   // 8B-aligned
    }
}

// ---------------------------------------------------------------------------
// Fused kernel, block = (batch b, 64-wide spatial tile), 256 thr, 27.5 KB,
// 5 blocks/CU:
//  Phase 0: stage x -> packed bf16 LDS sx[0][c][l] (256 B row runs).
//  Phase 1: winq per (c = lane, Q = wave); edges 64/65 brute-force by 192
//           threads. Then the C(x) half-GEMM (depends only on sx[0]) runs
//           BEFORE the mm barrier -- fills the barrier wait with MFMA.
//  Phase 2: after barrier, C(mm) half-GEMM; epilogue out1 = C(mm),
//           out0 = C(x) - C(mm).
// ---------------------------------------------------------------------------
__global__ __launch_bounds__(256, 5) void fused4(
    const float* __restrict__ x,
    const float* __restrict__ gw,
    const float* __restrict__ gb,
    const unsigned short* __restrict__ aw,
    float* __restrict__ out0,
    float* __restrict__ out1)
{
    __shared__ __align__(16) unsigned short sx[2][TT + 2][LROW];  // [0]=x,[1]=mm

    int b = blockIdx.x;
    int t0 = blockIdx.y * TT;
    size_t xb = (size_t)b * NL * NC;

    int lane = threadIdx.x & 63;
    int wv = threadIdx.x >> 6;
    int lr = lane & 15, lk = lane >> 4;

    // ---- Phase 0: stage x -> sx[0] ----
    for (int u = threadIdx.x; u < 768; u += 256) {
        int l2 = u >> 4, cq = u & 15;
        const float* p0 = x + xb + (size_t)(2 * l2) * NC + t0 + 4 * cq;
        f32x4 a = *(const f32x4*)p0;
        f32x4 bv = *(const f32x4*)(p0 + NC);
#pragma unroll
        for (int j = 0; j < 4; ++j)
            *(unsigned*)(&sx[0][1 + 4 * cq + j][2 * l2]) = cvt_pk_bf16(a[j], bv[j]);
    }
    if (threadIdx.x < 96) {
        int u = threadIdx.x;
        int e = u / 48, l2 = u - e * 48;
        int t = e ? ((t0 + TT) & (NC - 1)) : ((t0 - 1) & (NC - 1));
        int c = e ? 65 : 0;
        const float* p0 = x + xb + (size_t)(2 * l2) * NC + t;
        *(unsigned*)(&sx[0][c][2 * l2]) = cvt_pk_bf16(p0[0], p0[NC]);
    }
    __syncthreads();

    // ---- Phase 1: decomp -> sx[1] (mm only) ----
    {
        f32x2 w01 = {gw[0] * LOG2E, gw[1] * LOG2E};
        f32x2 b01 = {gb[0] * LOG2E, gb[1] * LOG2E};
        float w2 = gw[2] * LOG2E, b2 = gb[2] * LOG2E;

        {
            const unsigned* srow = (const unsigned*)&sx[0][lane][0];
            unsigned short* mrow = &sx[1][lane][0];
            if (wv == 0)      winq<0>(srow, mrow, w01, b01, w2, b2);
            else if (wv == 1) winq<1>(srow, mrow, w01, b01, w2, b2);
            else if (wv == 2) winq<2>(srow, mrow, w01, b01, w2, b2);
            else              winq<3>(srow, mrow, w01, b01, w2, b2);
        }
        // edge columns 64,65: 192 threads, one element each
        if (threadIdx.x < 192) {
            int ce = 64 + (threadIdx.x & 1);
            int l  = threadIdx.x >> 1;            // 0..95
            const unsigned short* col = &sx[0][ce][0];
            float s5 = 0.0f, s13 = 0.0f, s25 = 0.0f;
#pragma unroll
            for (int d = -12; d <= 12; ++d) {
                int li = l + d; li = li < 0 ? 0 : (li > 95 ? 95 : li);
                float v = __uint_as_float(((unsigned)col[li]) << 16);
                s25 += v;
                if (d >= -6 && d <= 6) s13 += v;
                if (d >= -2 && d <= 2) s5 += v;
            }
            float xl = __uint_as_float(((unsigned)col[l]) << 16);
            float e0 = fexp2(fmaf(xl, w01.x, b01.x));
            float e1 = fexp2(fmaf(xl, w01.y, b01.y));
            float e2 = fexp2(fmaf(xl, w2, b2));
            float inv = frcp(e0 + e1 + e2);
            float mmv = fmaf(s5 * 0.2f, e0,
                        fmaf(s13 * (1.0f / 13.0f), e1,
                             s25 * 0.04f * e2)) * inv;
            sx[1][ce][l] = (unsigned short)(cvt_pk_bf16(mmv, mmv) & 0xffffu);
        }
    }

    // ---- C(x) half-GEMM: depends only on sx[0], runs before the barrier ----
    int mg = wv & 1, ng = wv >> 1;
    const unsigned short* abase = aw + (size_t)(mg * 48 + lr) * KTOT + lk * 8;
    short8 aCur[3], aNxt[3];
#pragma unroll
    for (int mt = 0; mt < 3; ++mt)
        aCur[mt] = *(const short8*)(abase + mt * 16 * KTOT);

    f32x4 accx[3][2] = {}, accm[3][2] = {};

#pragma unroll
    for (int ks = 0; ks < 9; ++ks) {
        if (ks < 8) {
#pragma unroll
            for (int mt = 0; mt < 3; ++mt)
                aNxt[mt] = *(const short8*)(abase + mt * 16 * KTOT + (ks + 1) * 32);
        }
        const int tau = ks / 3;
        const int i0 = (ks - tau * 3) * 32;
        short8 bfx[2];
#pragma unroll
        for (int nt = 0; nt < 2; ++nt) {
            int r = ng * 32 + nt * 16 + lr + tau;   // LDS row = local t + tau (<=65)
            bfx[nt] = *(const short8*)(&sx[0][r][i0 + lk * 8]);
        }
#pragma unroll
        for (int mt = 0; mt < 3; ++mt)
#pragma unroll
            for (int nt = 0; nt < 2; ++nt)
                accx[mt][nt] = __builtin_amdgcn_mfma_f32_16x16x32_bf16(
                    aCur[mt], bfx[nt], accx[mt][nt], 0, 0, 0);
#pragma unroll
        for (int mt = 0; mt < 3; ++mt) aCur[mt] = aNxt[mt];
    }

    // reload A for the mm pass; loads issue before the barrier, latency
    // hides in the barrier wait
#pragma unroll
    for (int mt = 0; mt < 3; ++mt)
        aCur[mt] = *(const short8*)(abase + mt * 16 * KTOT);

    __syncthreads();

    // ---- C(mm) half-GEMM ----
#pragma unroll
    for (int ks = 0; ks < 9; ++ks) {
        if (ks < 8) {
#pragma unroll
            for (int mt = 0; mt < 3; ++mt)
                aNxt[mt] = *(const short8*)(abase + mt * 16 * KTOT + (ks + 1) * 32);
        }
        const int tau = ks / 3;
        const int i0 = (ks - tau * 3) * 32;
        short8 bfm[2];
#pragma unroll
        for (int nt = 0; nt < 2; ++nt) {
            int r = ng * 32 + nt * 16 + lr + tau;
            bfm[nt] = *(const short8*)(&sx[1][r][i0 + lk * 8]);
        }
#pragma unroll
        for (int mt = 0; mt < 3; ++mt)
#pragma unroll
            for (int nt = 0; nt < 2; ++nt)
                accm[mt][nt] = __builtin_amdgcn_mfma_f32_16x16x32_bf16(
                    aCur[mt], bfm[nt], accm[mt][nt], 0, 0, 0);
#pragma unroll
        for (int mt = 0; mt < 3; ++mt) aCur[mt] = aNxt[mt];
    }

    // epilogue: C/D layout col = lane&15 (t), row = (lane>>4)*4 + reg (o)
    // out1 = C(mm); out0 = C(x) - C(mm)
    int tw = t0 + ng * 32 + lr;
#pragma unroll
    for (int mt = 0; mt < 3; ++mt) {
        int o0 = mg * 48 + mt * 16 + lk * 4;
#pragma unroll
        for (int nt = 0; nt < 2; ++nt) {
#pragma unroll
            for (int r4 = 0; r4 < 4; ++r4) {
                size_t idx = xb + (size_t)(o0 + r4) * NC + tw + nt * 16;
                float vm = accm[mt][nt][r4];
                out1[idx] = vm;
                out0[idx] = accx[mt][nt][r4] - vm;
            }
        }
    }
}

extern "C" void kernel_launch(void* const* d_in, const int* in_sizes, int n_in,
                              void* d_out, int out_size, void* d_ws, size_t ws_size,
                              hipStream_t stream)
{
    const float* x      = (const float*)d_in[0];
    const float* conv_w = (const float*)d_in[1];
    const float* gate_w = (const float*)d_in[2];
    const float* gate_b = (const float*)d_in[3];

    float* out0 = (float*)d_out;
    float* out1 = out0 + (size_t)NB * NL * NC;

    unsigned short* awb = (unsigned short*)d_ws;   // [96][288] bf16

    prep_aw<<<dim3((NL * KTOT + 255) / 256), 256, 0, stream>>>(conv_w, awb);
    fused4<<<dim3(NB, NC / TT), 256, 0, stream>>>(x, gate_w, gate_b, awb, out0, out1);
}

// Round 12
// 44.142 us; speedup vs baseline: 1.2511x; 1.2511x over previous
//
#include <hip/hip_runtime.h>
#include <hip/hip_bf16.h>

typedef __attribute__((ext_vector_type(8))) short short8;
typedef __attribute__((ext_vector_type(8))) unsigned short u16x8;
typedef __attribute__((ext_vector_type(4))) unsigned short u16x4;
typedef __attribute__((ext_vector_type(4))) float f32x4;

constexpr int NB = 64;     // batch
constexpr int NL = 96;     // time / conv channels
constexpr int NC = 2048;   // feature / conv spatial
constexpr int TT = 64;     // conv spatial tile per block
constexpr int KTOT = 288;  // conv GEMM K = 96 ch * 3 taps, k = tau*96 + i
constexpr int LROW = 104;  // GEMM LDS row pitch in bf16 (52 dw, 16B-aligned)
constexpr int WPITCH = 49; // winq x-copy row pitch in dwords: odd -> conflict-free
constexpr float LOG2E = 1.44269504088896340736f;

__device__ inline unsigned short f2bf(float f) {
    union { float f; unsigned u; } v; v.f = f;
    unsigned r = v.u + 0x7fff + ((v.u >> 16) & 1);   // RNE
    return (unsigned short)(r >> 16);
}
__device__ inline unsigned cvt_pk_bf16(float lo, float hi) {
    unsigned r;
    asm("v_cvt_pk_bf16_f32 %0, %1, %2" : "=v"(r) : "v"(lo), "v"(hi));
    return r;
}
__device__ inline float fexp2(float x) {
    float r; asm("v_exp_f32 %0, %1" : "=v"(r) : "v"(x)); return r;
}
__device__ inline float frcp(float x) {
    float r; asm("v_rcp_f32 %0, %1" : "=v"(r) : "v"(x)); return r;
}
__device__ inline float bflo(unsigned d) { return __uint_as_float(d << 16); }
__device__ inline float bfhi(unsigned d) { return __uint_as_float(d & 0xffff0000u); }

// ---------------------------------------------------------------------------
// Weight permute+convert: Aw[o][k], k = tau*96 + i, bf16.
// ---------------------------------------------------------------------------
__global__ void prep_aw(const float* __restrict__ w, unsigned short* __restrict__ aw)
{
    int idx = blockIdx.x * 256 + threadIdx.x;
    if (idx >= NL * KTOT) return;
    int o = idx / KTOT, k = idx - o * KTOT;
    int tau = k / NL, i = k - tau * NL;
    aw[idx] = f2bf(w[(o * NL + i) * 3 + tau]);
}

// ---------------------------------------------------------------------------
// winq<Q>: spill-free sliding-window decomp for quarter Q (l = 24Q..24Q+23)
// of one column. Reads <=24 packed-bf16 dwords from the CONFLICT-FREE
// pitch-49 x copy (static indices, clamp = replicate pad), three moving
// means + softmax gate, mm -> GEMM-layout LDS. R9-exact math.
// ---------------------------------------------------------------------------
template<int Q>
__device__ __forceinline__ void winq(
    const unsigned* __restrict__ srow,     // &sxw[c*49]
    unsigned short* __restrict__ mrow,     // &sx[1][c][0]
    float w0, float w1, float w2, float b0, float b1, float b2)
{
    constexpr int L0 = Q * 24;
    constexpr int DW0 = (Q == 0) ? 0 : 12 * Q - 6;
    constexpr int NDW = (Q == 0 || Q == 3) ? 18 : 24;

    unsigned dv[NDW];
#pragma unroll
    for (int d = 0; d < NDW; ++d) dv[d] = srow[DW0 + d];

#define CLMP(r) ((r) < 0 ? 0 : ((r) > 95 ? 95 : (r)))
#define VAL(r) ((CLMP(r) & 1) ? bfhi(dv[(CLMP(r) >> 1) - DW0]) \
                              : bflo(dv[(CLMP(r) >> 1) - DW0]))

    float s5 = 0.0f, s13 = 0.0f, s25 = 0.0f;
#pragma unroll
    for (int d = -12; d <= 12; ++d) {
        float v = VAL(L0 + d);
        s25 += v;
        if (d >= -6 && d <= 6) s13 += v;
        if (d >= -2 && d <= 2) s5 += v;
    }

    unsigned md[12];
    float pm = 0.0f;
#pragma unroll
    for (int i = 0; i < 24; ++i) {
        const int l = L0 + i;
        if (i > 0) {
            s25 += VAL(l + 12) - VAL(l - 13);
            s13 += VAL(l + 6)  - VAL(l - 7);
            s5  += VAL(l + 2)  - VAL(l - 3);
        }
        float xl = VAL(l);
        float e0 = fexp2(fmaf(xl, w0, b0));
        float e1 = fexp2(fmaf(xl, w1, b1));
        float e2 = fexp2(fmaf(xl, w2, b2));
        float inv = frcp(e0 + e1 + e2);
        float mmv = fmaf(s5 * 0.2f, e0,
                    fmaf(s13 * (1.0f / 13.0f), e1,
                         s25 * 0.04f * e2)) * inv;
        if ((i & 1) == 0) pm = mmv;
        else              md[i >> 1] = cvt_pk_bf16(pm, mmv);
    }
#undef VAL
#undef CLMP

#pragma unroll
    for (int v = 0; v < 6; ++v) {
        union { u16x4 vv; unsigned d[2]; } o;
        o.d[0] = md[2 * v]; o.d[1] = md[2 * v + 1];
        *(u16x4*)(mrow + L0 + 4 * v) = o.vv;   // 8B-aligned
    }
}

// ---------------------------------------------------------------------------
// Fused kernel, block = (batch b, 64-wide spatial tile), 256 thr, 40.4 KB,
// 3 blocks/CU:
//  Phase 0: stage x -> sx[0] (GEMM layout, pitch 104 bf16) AND sxw (winq
//           layout, pitch 49 dw, conflict-free reads+writes). 256 B runs.
//  Phase 1: winq per (c = lane, Q = wave) from sxw; edges 64/65 brute-force
//           by 192 threads from sx[0]. Writes mm only (linearity).
//  Phase 2: both convs as one bf16 MFMA GEMM over {sx[0]=x, sx[1]=mm};
//           out1 = C(mm), out0 = C(x) - C(mm).
// ---------------------------------------------------------------------------
__global__ __launch_bounds__(256, 3) void fused5(
    const float* __restrict__ x,
    const float* __restrict__ gw,
    const float* __restrict__ gb,
    const unsigned short* __restrict__ aw,
    float* __restrict__ out0,
    float* __restrict__ out1)
{
    __shared__ __align__(16) unsigned short sx[2][TT + 2][LROW];  // [0]=x,[1]=mm
    __shared__ unsigned sxw[(TT + 2) * WPITCH];                   // winq x copy

    int b = blockIdx.x;
    int t0 = blockIdx.y * TT;
    size_t xb = (size_t)b * NL * NC;

    int lane = threadIdx.x & 63;
    int wv = threadIdx.x >> 6;
    int lr = lane & 15, lk = lane >> 4;

    // ---- Phase 0: stage x -> sx[0] + sxw ----
    for (int u = threadIdx.x; u < 768; u += 256) {
        int l2 = u >> 4, cq = u & 15;
        const float* p0 = x + xb + (size_t)(2 * l2) * NC + t0 + 4 * cq;
        f32x4 a = *(const f32x4*)p0;
        f32x4 bv = *(const f32x4*)(p0 + NC);
#pragma unroll
        for (int j = 0; j < 4; ++j) {
            unsigned pk = cvt_pk_bf16(a[j], bv[j]);
            int c = 1 + 4 * cq + j;
            *(unsigned*)(&sx[0][c][2 * l2]) = pk;
            sxw[c * WPITCH + l2] = pk;
        }
    }
    if (threadIdx.x < 96) {
        int u = threadIdx.x;
        int e = u / 48, l2 = u - e * 48;
        int t = e ? ((t0 + TT) & (NC - 1)) : ((t0 - 1) & (NC - 1));
        int c = e ? 65 : 0;
        const float* p0 = x + xb + (size_t)(2 * l2) * NC + t;
        unsigned pk = cvt_pk_bf16(p0[0], p0[NC]);
        *(unsigned*)(&sx[0][c][2 * l2]) = pk;
        if (!e) sxw[l2] = pk;   // winq needs column 0
    }
    __syncthreads();

    // ---- Phase 1: decomp -> sx[1] (mm only) ----
    {
        float w0 = gw[0] * LOG2E, w1 = gw[1] * LOG2E, w2 = gw[2] * LOG2E;
        float b0 = gb[0] * LOG2E, b1 = gb[1] * LOG2E, b2 = gb[2] * LOG2E;

        // main columns 0..63: c = lane, Q = wave (wave-uniform template)
        {
            const unsigned* srow = &sxw[lane * WPITCH];
            unsigned short* mrow = &sx[1][lane][0];
            if (wv == 0)      winq<0>(srow, mrow, w0, w1, w2, b0, b1, b2);
            else if (wv == 1) winq<1>(srow, mrow, w0, w1, w2, b0, b1, b2);
            else if (wv == 2) winq<2>(srow, mrow, w0, w1, w2, b0, b1, b2);
            else              winq<3>(srow, mrow, w0, w1, w2, b0, b1, b2);
        }
        // edge columns 64,65: 192 threads, one element each
        if (threadIdx.x < 192) {
            int ce = 64 + (threadIdx.x & 1);
            int l  = threadIdx.x >> 1;            // 0..95
            const unsigned short* col = &sx[0][ce][0];
            float s5 = 0.0f, s13 = 0.0f, s25 = 0.0f;
#pragma unroll
            for (int d = -12; d <= 12; ++d) {
                int li = l + d; li = li < 0 ? 0 : (li > 95 ? 95 : li);
                float v = __uint_as_float(((unsigned)col[li]) << 16);
                s25 += v;
                if (d >= -6 && d <= 6) s13 += v;
                if (d >= -2 && d <= 2) s5 += v;
            }
            float xl = __uint_as_float(((unsigned)col[l]) << 16);
            float e0 = fexp2(fmaf(xl, w0, b0));
            float e1 = fexp2(fmaf(xl, w1, b1));
            float e2 = fexp2(fmaf(xl, w2, b2));
            float inv = frcp(e0 + e1 + e2);
            float mmv = fmaf(s5 * 0.2f, e0,
                        fmaf(s13 * (1.0f / 13.0f), e1,
                             s25 * 0.04f * e2)) * inv;
            sx[1][ce][l] = (unsigned short)(cvt_pk_bf16(mmv, mmv) & 0xffffu);
        }
    }

    // main-GEMM A prefetch (L2-hot 55 KB), issued before the barrier
    int mg = wv & 1, ng = wv >> 1;
    const unsigned short* abase = aw + (size_t)(mg * 48 + lr) * KTOT + lk * 8;
    short8 aCur[3], aNxt[3];
#pragma unroll
    for (int mt = 0; mt < 3; ++mt)
        aCur[mt] = *(const short8*)(abase + mt * 16 * KTOT);

    __syncthreads();

    // ---- Phase 2: conv GEMM over B-tiles {sx[0]=x, sx[1]=mm} ----
    f32x4 acc[3][2][2] = {};

#pragma unroll
    for (int ks = 0; ks < 9; ++ks) {
        if (ks < 8) {
#pragma unroll
            for (int mt = 0; mt < 3; ++mt)
                aNxt[mt] = *(const short8*)(abase + mt * 16 * KTOT + (ks + 1) * 32);
        }
        const int tau = ks / 3;
        const int i0 = (ks - tau * 3) * 32;
        short8 bfx[2], bfm[2];
#pragma unroll
        for (int nt = 0; nt < 2; ++nt) {
            int r = ng * 32 + nt * 16 + lr + tau;   // LDS row = local t + tau (<=65)
            bfx[nt] = *(const short8*)(&sx[0][r][i0 + lk * 8]);
            bfm[nt] = *(const short8*)(&sx[1][r][i0 + lk * 8]);
        }
#pragma unroll
        for (int mt = 0; mt < 3; ++mt)
#pragma unroll
            for (int nt = 0; nt < 2; ++nt) {
                acc[mt][nt][0] = __builtin_amdgcn_mfma_f32_16x16x32_bf16(
                    aCur[mt], bfx[nt], acc[mt][nt][0], 0, 0, 0);
                acc[mt][nt][1] = __builtin_amdgcn_mfma_f32_16x16x32_bf16(
                    aCur[mt], bfm[nt], acc[mt][nt][1], 0, 0, 0);
            }
#pragma unroll
        for (int mt = 0; mt < 3; ++mt) aCur[mt] = aNxt[mt];
    }

    // epilogue: C/D layout col = lane&15 (t), row = (lane>>4)*4 + reg (o)
    // out1 = C(mm); out0 = C(x) - C(mm)
    int tw = t0 + ng * 32 + lr;
#pragma unroll
    for (int mt = 0; mt < 3; ++mt) {
        int o0 = mg * 48 + mt * 16 + lk * 4;
#pragma unroll
        for (int nt = 0; nt < 2; ++nt) {
#pragma unroll
            for (int r4 = 0; r4 < 4; ++r4) {
                size_t idx = xb + (size_t)(o0 + r4) * NC + tw + nt * 16;
                float vm = acc[mt][nt][1][r4];
                out1[idx] = vm;
                out0[idx] = acc[mt][nt][0][r4] - vm;
            }
        }
    }
}

extern "C" void kernel_launch(void* const* d_in, const int* in_sizes, int n_in,
                              void* d_out, int out_size, void* d_ws, size_t ws_size,
                              hipStream_t stream)
{
    const float* x      = (const float*)d_in[0];
    const float* conv_w = (const float*)d_in[1];
    const float* gate_w = (const float*)d_in[2];
    const float* gate_b = (const float*)d_in[3];

    float* out0 = (float*)d_out;
    float* out1 = out0 + (size_t)NB * NL * NC;

    unsigned short* awb = (unsigned short*)d_ws;   // [96][288] bf16

    prep_aw<<<dim3((NL * KTOT + 255) / 256), 256, 0, stream>>>(conv_w, awb);
    fused5<<<dim3(NB, NC / TT), 256, 0, stream>>>(x, gate_w, gate_b, awb, out0, out1);
}